// Round 1
// baseline (445.111 us; speedup 1.0000x reference)
//
#include <hip/hip_runtime.h>
#include <float.h>
#include <math.h>

// AdvancedLossFunction: total = 1.0*occupancy + 0.1*smoothness + 0.01*sparsity + 0.1*consistency
//   occupancy  = BCE(pred, targets), pred clipped to [1e-7, 1-1e-7]
//   smoothness = mean |pred_i - pred_{3NN(i)}| over (N,3)
//   sparsity   = mean |features|
//   consistency= mean (pred - targets)^2
// N=16384 points in 3D; brute-force 3-NN, j-dimension chunked for CU parallelism.

constexpr int   N_ = 16384;
constexpr int   F_ = 64;
constexpr float OCC_W = 1.0f, SMOOTH_W = 0.1f, SPARSE_W = 0.01f, CONS_W = 0.1f;
constexpr float EPS_ = 1e-7f;

// ws layout:
//   byte 0    : float acc[4]  {occ_sum, cons_sum, sparse_sum, smooth_sum}
//   byte 256  : float4 packed[N]   (x, y, z, pred)
//   byte 256 + N*16 : float2 cand[CHUNKS][N][3]  (d2, pred_of_neighbor)

__global__ void reduce_kernel(const float* __restrict__ pred,
                              const float* __restrict__ targ,
                              const float* __restrict__ feat,
                              float* __restrict__ acc) {
  int tid = blockIdx.x * blockDim.x + threadIdx.x;
  int nthreads = gridDim.x * blockDim.x;
  float s_sp = 0.f;
  const float4* f4 = (const float4*)feat;
  for (int t = tid; t < N_ * F_ / 4; t += nthreads) {
    float4 v = f4[t];
    s_sp += fabsf(v.x) + fabsf(v.y) + fabsf(v.z) + fabsf(v.w);
  }
  float s_occ = 0.f, s_cons = 0.f;
  for (int i = tid; i < N_; i += nthreads) {
    float pr = pred[i];
    float t  = targ[i];
    float p  = fminf(fmaxf(pr, EPS_), 1.0f - EPS_);
    s_occ -= t * logf(p) + (1.0f - t) * log1pf(-p);
    float d = pr - t;
    s_cons += d * d;
  }
  // wave-level reduction (wave = 64 lanes)
  for (int off = 32; off > 0; off >>= 1) {
    s_sp   += __shfl_down(s_sp, off);
    s_occ  += __shfl_down(s_occ, off);
    s_cons += __shfl_down(s_cons, off);
  }
  if ((threadIdx.x & 63) == 0) {
    atomicAdd(&acc[0], s_occ);
    atomicAdd(&acc[1], s_cons);
    atomicAdd(&acc[2], s_sp);
  }
}

__global__ void pack_kernel(const float* __restrict__ pts,
                            const float* __restrict__ pred,
                            float4* __restrict__ packed) {
  int i = blockIdx.x * blockDim.x + threadIdx.x;
  if (i < N_) {
    packed[i] = make_float4(pts[3 * i], pts[3 * i + 1], pts[3 * i + 2], pred[i]);
  }
}

template <int CHUNKS>
__global__ __launch_bounds__(256) void knn_kernel(const float4* __restrict__ packed,
                                                  float2* __restrict__ cand) {
  constexpr int CHUNK  = N_ / CHUNKS;   // j's per chunk (multiple of 1024)
  constexpr int ITEMS  = 4;             // i's per thread
  constexpr int IPG    = ITEMS * 256;   // i's per block = 1024
  constexpr int IGROUPS = N_ / IPG;     // 16
  int igrp  = blockIdx.x % IGROUPS;
  int chunk = blockIdx.x / IGROUPS;

  __shared__ float4 tile[1024];

  int ibase = igrp * IPG + threadIdx.x;
  float px[ITEMS], py[ITEMS], pz[ITEMS];
  int   idx[ITEMS];
  float b0[ITEMS], b1[ITEMS], b2[ITEMS];   // top-3 smallest d2 (sorted)
  float q0[ITEMS], q1[ITEMS], q2[ITEMS];   // pred of those neighbors
#pragma unroll
  for (int k = 0; k < ITEMS; ++k) {
    int i = ibase + k * 256;
    idx[k] = i;
    float4 p = packed[i];
    px[k] = p.x; py[k] = p.y; pz[k] = p.z;
    b0[k] = b1[k] = b2[k] = FLT_MAX;
    q0[k] = q1[k] = q2[k] = 0.f;
  }

  for (int sub = 0; sub < CHUNK; sub += 1024) {
    __syncthreads();
    for (int t = threadIdx.x; t < 1024; t += 256)
      tile[t] = packed[chunk * CHUNK + sub + t];
    __syncthreads();
    for (int jj = 0; jj < 1024; ++jj) {
      float4 q = tile[jj];               // wave-uniform address -> LDS broadcast
      int jg = chunk * CHUNK + sub + jj;
#pragma unroll
      for (int k = 0; k < ITEMS; ++k) {
        float dx = px[k] - q.x, dy = py[k] - q.y, dz = pz[k] - q.z;
        float d2 = dx * dx + dy * dy + dz * dz;
        if (jg == idx[k]) d2 = FLT_MAX;  // exclude self
        if (d2 < b2[k]) {                // rare: whole wave usually skips
          if (d2 < b1[k]) {
            b2[k] = b1[k]; q2[k] = q1[k];
            if (d2 < b0[k]) { b1[k] = b0[k]; q1[k] = q0[k]; b0[k] = d2; q0[k] = q.w; }
            else            { b1[k] = d2;    q1[k] = q.w; }
          } else { b2[k] = d2; q2[k] = q.w; }
        }
      }
    }
  }

#pragma unroll
  for (int k = 0; k < ITEMS; ++k) {
    float2* c = &cand[((size_t)chunk * N_ + idx[k]) * 3];
    c[0] = make_float2(b0[k], q0[k]);
    c[1] = make_float2(b1[k], q1[k]);
    c[2] = make_float2(b2[k], q2[k]);
  }
}

__global__ void merge_kernel(const float* __restrict__ pred,
                             const float2* __restrict__ cand,
                             int chunks,
                             float* __restrict__ acc) {
  int i = blockIdx.x * blockDim.x + threadIdx.x;
  float s = 0.f;
  if (i < N_) {
    float b0 = FLT_MAX, b1 = FLT_MAX, b2 = FLT_MAX;
    float q0 = 0.f, q1 = 0.f, q2 = 0.f;
    for (int c = 0; c < chunks; ++c) {
      const float2* cc = &cand[((size_t)c * N_ + i) * 3];
      for (int m = 0; m < 3; ++m) {
        float2 v = cc[m];
        float d2 = v.x, qw = v.y;
        if (d2 < b2) {
          if (d2 < b1) {
            b2 = b1; q2 = q1;
            if (d2 < b0) { b1 = b0; q1 = q0; b0 = d2; q0 = qw; }
            else         { b1 = d2; q1 = qw; }
          } else { b2 = d2; q2 = qw; }
        }
      }
    }
    float pi = pred[i];
    s = fabsf(pi - q0) + fabsf(pi - q1) + fabsf(pi - q2);
  }
  for (int off = 32; off > 0; off >>= 1) s += __shfl_down(s, off);
  if ((threadIdx.x & 63) == 0) atomicAdd(&acc[3], s);
}

__global__ void finalize_kernel(const float* __restrict__ acc, float* __restrict__ out) {
  if (threadIdx.x == 0 && blockIdx.x == 0) {
    float occ    = acc[0] / (float)N_;
    float cons   = acc[1] / (float)N_;
    float sparse = acc[2] / (float)(N_ * F_);
    float smooth = acc[3] / (float)(N_ * 3);
    out[0] = OCC_W * occ + SMOOTH_W * smooth + SPARSE_W * sparse + CONS_W * cons;
  }
}

extern "C" void kernel_launch(void* const* d_in, const int* in_sizes, int n_in,
                              void* d_out, int out_size, void* d_ws, size_t ws_size,
                              hipStream_t stream) {
  const float* pred = (const float*)d_in[0];
  const float* targ = (const float*)d_in[1];
  const float* feat = (const float*)d_in[2];
  const float* pts  = (const float*)d_in[3];
  float* out = (float*)d_out;

  char*   ws     = (char*)d_ws;
  float*  acc    = (float*)ws;
  float4* packed = (float4*)(ws + 256);
  float2* cand   = (float2*)(ws + 256 + (size_t)N_ * 16);

  hipMemsetAsync(acc, 0, 4 * sizeof(float), stream);

  reduce_kernel<<<256, 256, 0, stream>>>(pred, targ, feat, acc);
  pack_kernel<<<N_ / 256, 256, 0, stream>>>(pts, pred, packed);

  size_t base   = 256 + (size_t)N_ * 16;
  size_t need16 = base + (size_t)16 * N_ * 3 * sizeof(float2);
  size_t need4  = base + (size_t)4  * N_ * 3 * sizeof(float2);
  int chunks;
  if (ws_size >= need16)      chunks = 16;
  else if (ws_size >= need4)  chunks = 4;
  else                        chunks = 1;

  if (chunks == 16)     knn_kernel<16><<<16 * 16, 256, 0, stream>>>(packed, cand);
  else if (chunks == 4) knn_kernel<4><<<16 * 4, 256, 0, stream>>>(packed, cand);
  else                  knn_kernel<1><<<16 * 1, 256, 0, stream>>>(packed, cand);

  merge_kernel<<<N_ / 256, 256, 0, stream>>>(pred, cand, chunks, acc);
  finalize_kernel<<<1, 64, 0, stream>>>(acc, out);
}

// Round 2
// 218.461 us; speedup vs baseline: 2.0375x; 2.0375x over previous
//
#include <hip/hip_runtime.h>
#include <float.h>
#include <math.h>
#include <type_traits>

// AdvancedLossFunction: total = 1.0*occ + 0.1*smooth + 0.01*sparse + 0.1*cons
// N=16384 pts in 3D; brute-force 3-NN (j chunked for occupancy), fused reductions.

constexpr int   N_ = 16384;
constexpr int   F_ = 64;
constexpr float OCC_W = 1.0f, SMOOTH_W = 0.1f, SPARSE_W = 0.01f, CONS_W = 0.1f;
constexpr float EPS_ = 1e-7f;

// ws layout:
//   byte 0   : float acc[4]  {occ_sum, cons_sum, sparse_sum, smooth_sum}
//   byte 16  : unsigned done_counter
//   byte 256 : float4 packed[N]  (x,y,z,pred)
//   byte 256+N*16 : float2 cand[CHUNKS*3][N]   (d2, pred_of_neighbor), coalesced in i

__global__ void reduce_pack_kernel(const float* __restrict__ pred,
                                   const float* __restrict__ targ,
                                   const float* __restrict__ feat,
                                   const float* __restrict__ pts,
                                   float* __restrict__ acc,
                                   float4* __restrict__ packed) {
  int tid = blockIdx.x * blockDim.x + threadIdx.x;     // grid = 64*256 = 16384 == N_
  float s_sp = 0.f;
  const float4* f4 = (const float4*)feat;
#pragma unroll 4
  for (int t = tid; t < N_ * F_ / 4; t += N_) {
    float4 v = f4[t];
    s_sp += fabsf(v.x) + fabsf(v.y) + fabsf(v.z) + fabsf(v.w);
  }
  float pr = pred[tid];
  float t  = targ[tid];
  float p  = fminf(fmaxf(pr, EPS_), 1.0f - EPS_);
  float s_occ  = -(t * logf(p) + (1.0f - t) * log1pf(-p));
  float d = pr - t;
  float s_cons = d * d;
  packed[tid] = make_float4(pts[3 * tid], pts[3 * tid + 1], pts[3 * tid + 2], pr);

  for (int off = 32; off > 0; off >>= 1) {
    s_sp   += __shfl_down(s_sp, off);
    s_occ  += __shfl_down(s_occ, off);
    s_cons += __shfl_down(s_cons, off);
  }
  if ((threadIdx.x & 63) == 0) {
    atomicAdd(&acc[0], s_occ);
    atomicAdd(&acc[1], s_cons);
    atomicAdd(&acc[2], s_sp);
  }
}

template <int CHUNKS>
__global__ __launch_bounds__(256) void knn_kernel(const float4* __restrict__ packed,
                                                  float2* __restrict__ cand) {
  constexpr int CHUNK   = N_ / CHUNKS;
  constexpr int ITEMS   = 4;
  constexpr int IPG     = 1024;                 // i's per block
  constexpr int IGROUPS = N_ / IPG;             // 16
  constexpr int TILE    = (CHUNK < 1024) ? CHUNK : 1024;  // pow2

  int igrp  = blockIdx.x % IGROUPS;
  int chunk = blockIdx.x / IGROUPS;
  int j0    = chunk * CHUNK;

  __shared__ float4 tile[TILE];

  int   idx[ITEMS];
  float px[ITEMS], py[ITEMS], pz[ITEMS];
  float b0[ITEMS], b1[ITEMS], b2[ITEMS];
  float q0[ITEMS], q1[ITEMS], q2[ITEMS];
#pragma unroll
  for (int k = 0; k < ITEMS; ++k) {
    int i = igrp * IPG + threadIdx.x + k * 256;
    idx[k] = i;
    float4 p = packed[i];
    px[k] = p.x; py[k] = p.y; pz[k] = p.z;
    b0[k] = b1[k] = b2[k] = FLT_MAX;
    q0[k] = q1[k] = q2[k] = 0.f;
  }

  // does this block's j-range intersect its i-range? (only those need self-test)
  int ilo = igrp * IPG, ihi = ilo + IPG;
  bool overlap = (j0 < ihi) && (ilo < j0 + CHUNK);

  auto scan = [&](auto self_tag) {
    constexpr bool SELF = decltype(self_tag)::value;
    for (int sub = 0; sub < CHUNK; sub += TILE) {
      __syncthreads();
      for (int t = threadIdx.x; t < TILE; t += 256)
        tile[t] = packed[j0 + sub + t];
      __syncthreads();
      int jg0 = j0 + sub;
      float4 q = tile[0];
      for (int jj = 0; jj < TILE; ++jj) {
        float4 qn = tile[(jj + 1) & (TILE - 1)];   // prefetch next (wave-uniform, broadcast)
        float d2a[ITEMS];
#pragma unroll
        for (int k = 0; k < ITEMS; ++k) {
          float dx = px[k] - q.x, dy = py[k] - q.y, dz = pz[k] - q.z;
          float d2 = fmaf(dz, dz, fmaf(dy, dy, dx * dx));
          if (SELF && (jg0 + jj == idx[k])) d2 = FLT_MAX;
          d2a[k] = d2;
        }
        float qw = q.w;
#pragma unroll
        for (int k = 0; k < ITEMS; ++k) {
          float d2 = d2a[k];
          if (d2 < b2[k]) {                       // rare — usually whole wave skips
            bool c0 = d2 < b0[k], c1 = d2 < b1[k];
            float nb2 = c1 ? b1[k] : d2;                      float nq2 = c1 ? q1[k] : qw;
            float nb1 = c0 ? b0[k] : (c1 ? d2 : b1[k]);       float nq1 = c0 ? q0[k] : (c1 ? qw : q1[k]);
            float nb0 = c0 ? d2 : b0[k];                      float nq0 = c0 ? qw : q0[k];
            b0[k] = nb0; b1[k] = nb1; b2[k] = nb2;
            q0[k] = nq0; q1[k] = nq1; q2[k] = nq2;
          }
        }
        q = qn;
      }
    }
  };
  if (overlap) scan(std::true_type{});
  else         scan(std::false_type{});

#pragma unroll
  for (int k = 0; k < ITEMS; ++k) {
    cand[((size_t)chunk * 3 + 0) * N_ + idx[k]] = make_float2(b0[k], q0[k]);
    cand[((size_t)chunk * 3 + 1) * N_ + idx[k]] = make_float2(b1[k], q1[k]);
    cand[((size_t)chunk * 3 + 2) * N_ + idx[k]] = make_float2(b2[k], q2[k]);
  }
}

__global__ void merge_finalize_kernel(const float* __restrict__ pred,
                                      const float2* __restrict__ cand,
                                      int chunks,
                                      float* __restrict__ acc,
                                      unsigned* __restrict__ done,
                                      float* __restrict__ out) {
  __shared__ float wsum[4];
  int i = blockIdx.x * 256 + threadIdx.x;   // grid = 64*256 = N_

  float b0 = FLT_MAX, b1 = FLT_MAX, b2 = FLT_MAX;
  float q0 = 0.f, q1 = 0.f, q2 = 0.f;
  for (int c = 0; c < chunks; ++c) {
    const float2* base = cand + (size_t)c * 3 * N_;
    float2 v0 = base[i];
    float2 v1 = base[N_ + i];
    float2 v2 = base[2 * N_ + i];
#pragma unroll
    for (int m = 0; m < 3; ++m) {
      float2 v = (m == 0) ? v0 : (m == 1) ? v1 : v2;
      float d2 = v.x, qw = v.y;
      if (d2 < b2) {
        bool c0 = d2 < b0, c1 = d2 < b1;
        float nb2 = c1 ? b1 : d2;                 float nq2 = c1 ? q1 : qw;
        float nb1 = c0 ? b0 : (c1 ? d2 : b1);     float nq1 = c0 ? q0 : (c1 ? qw : q1);
        float nb0 = c0 ? d2 : b0;                 float nq0 = c0 ? qw : q0;
        b0 = nb0; b1 = nb1; b2 = nb2; q0 = nq0; q1 = nq1; q2 = nq2;
      }
    }
  }
  float pi = pred[i];
  float s = fabsf(pi - q0) + fabsf(pi - q1) + fabsf(pi - q2);

  for (int off = 32; off > 0; off >>= 1) s += __shfl_down(s, off);
  if ((threadIdx.x & 63) == 0) wsum[threadIdx.x >> 6] = s;
  __syncthreads();

  if (threadIdx.x == 0) {
    float blocksum = wsum[0] + wsum[1] + wsum[2] + wsum[3];
    atomicAdd(&acc[3], blocksum);
    __threadfence();
    unsigned prev = atomicAdd(done, 1u);
    if (prev == (unsigned)(gridDim.x - 1)) {   // last block: finalize
      float occ  = atomicAdd(&acc[0], 0.f);
      float cons = atomicAdd(&acc[1], 0.f);
      float sp   = atomicAdd(&acc[2], 0.f);
      float sm   = atomicAdd(&acc[3], 0.f);
      out[0] = OCC_W * (occ / (float)N_)
             + CONS_W * (cons / (float)N_)
             + SPARSE_W * (sp / (float)(N_ * F_))
             + SMOOTH_W * (sm / (float)(N_ * 3));
    }
  }
}

extern "C" void kernel_launch(void* const* d_in, const int* in_sizes, int n_in,
                              void* d_out, int out_size, void* d_ws, size_t ws_size,
                              hipStream_t stream) {
  const float* pred = (const float*)d_in[0];
  const float* targ = (const float*)d_in[1];
  const float* feat = (const float*)d_in[2];
  const float* pts  = (const float*)d_in[3];
  float* out = (float*)d_out;

  char*     ws     = (char*)d_ws;
  float*    acc    = (float*)ws;
  unsigned* done   = (unsigned*)(ws + 16);
  float4*   packed = (float4*)(ws + 256);
  float2*   cand   = (float2*)(ws + 256 + (size_t)N_ * 16);

  hipMemsetAsync(ws, 0, 256, stream);

  reduce_pack_kernel<<<N_ / 256, 256, 0, stream>>>(pred, targ, feat, pts, acc, packed);

  size_t base = 256 + (size_t)N_ * 16;
  auto need = [&](int c) { return base + (size_t)c * 3 * N_ * sizeof(float2); };
  int chunks;
  if      (ws_size >= need(64)) chunks = 64;
  else if (ws_size >= need(32)) chunks = 32;
  else if (ws_size >= need(16)) chunks = 16;
  else                          chunks = 4;

  if (chunks == 64)      knn_kernel<64><<<16 * 64, 256, 0, stream>>>(packed, cand);
  else if (chunks == 32) knn_kernel<32><<<16 * 32, 256, 0, stream>>>(packed, cand);
  else if (chunks == 16) knn_kernel<16><<<16 * 16, 256, 0, stream>>>(packed, cand);
  else                   knn_kernel<4><<<16 * 4, 256, 0, stream>>>(packed, cand);

  merge_finalize_kernel<<<N_ / 256, 256, 0, stream>>>(pred, cand, chunks, acc, done, out);
}